// Round 1
// baseline (185.129 us; speedup 1.0000x reference)
//
#include <hip/hip_runtime.h>

#define DD 16
#define BB 8
#define NN 2048
#define WMAX 2.0f

// ---------------------------------------------------------------------------
// Main kernel: for each (e, o4) compute, for all b:
//   accp = sum_d xbar_pre[d,b,e] * dmap[d,e,o]
//   accd = sum_d Xd[d,b,e]       * dmap[d,e,o]
//   dW   = accp*A_p[e,o]*(Xpost[b,o]*relu(u_pot[b,o])) - accd*A_d[e,o]*relu(u_dep[b,o])
//   out      = W[b,e,o]                      (pre-update copy)
//   W_new    = clip(W + dW, 0, WMAX)
// e is wave-uniform (blockIdx only) -> coefficient loads scalarize.
// ---------------------------------------------------------------------------
__global__ __launch_bounds__(256) void clopath_main(
    const float* __restrict__ Xd,        // (D,B,N)
    const float* __restrict__ Xpost,     // (B,N)
    const float* __restrict__ xbar_pre,  // (D,B,N)
    const float* __restrict__ u_pot,     // (B,N)
    const float* __restrict__ u_dep,     // (B,N)
    const float* __restrict__ W,         // (B,N,N)
    const float* __restrict__ A_p,       // (N,N)
    const float* __restrict__ A_d,       // (N,N)
    const float* __restrict__ dmap,      // (D,N,N)
    float* __restrict__ out_W,           // (B,N,N)  pre-update copy
    float* __restrict__ out_Wnew)        // (B,N,N)
{
    // blocks_per_row = (N/4)/256 = 2
    const int e = blockIdx.x >> 1;                                   // uniform
    const int o = ((((int)blockIdx.x & 1) << 8) | (int)threadIdx.x) << 2;
    const size_t eo = (size_t)e * NN + o;

    const float4 ap = *reinterpret_cast<const float4*>(A_p + eo);
    const float4 ad = *reinterpret_cast<const float4*>(A_d + eo);

    float4 dm[DD];
#pragma unroll
    for (int d = 0; d < DD; ++d)
        dm[d] = *reinterpret_cast<const float4*>(dmap + (size_t)d * NN * NN + eo);

#pragma unroll
    for (int b = 0; b < BB; ++b) {
        float4 accp = make_float4(0.f, 0.f, 0.f, 0.f);
        float4 accd = make_float4(0.f, 0.f, 0.f, 0.f);
#pragma unroll
        for (int d = 0; d < DD; ++d) {
            const float xb = xbar_pre[(d * BB + b) * NN + e];  // wave-uniform
            const float xs = Xd[(d * BB + b) * NN + e];        // wave-uniform
            accp.x = fmaf(xb, dm[d].x, accp.x);
            accp.y = fmaf(xb, dm[d].y, accp.y);
            accp.z = fmaf(xb, dm[d].z, accp.z);
            accp.w = fmaf(xb, dm[d].w, accp.w);
            accd.x = fmaf(xs, dm[d].x, accd.x);
            accd.y = fmaf(xs, dm[d].y, accd.y);
            accd.z = fmaf(xs, dm[d].z, accd.z);
            accd.w = fmaf(xs, dm[d].w, accd.w);
        }

        const int bo = b * NN + o;
        const float4 xp = *reinterpret_cast<const float4*>(Xpost + bo);
        const float4 up = *reinterpret_cast<const float4*>(u_pot + bo);
        const float4 ud = *reinterpret_cast<const float4*>(u_dep + bo);

        const size_t widx = (size_t)b * NN * NN + eo;
        const float4 w4 = *reinterpret_cast<const float4*>(W + widx);

        float4 wn;
#define COMP(c)                                                          \
        {                                                                \
            const float gp = xp.c * fmaxf(up.c, 0.f);                    \
            const float gd = fmaxf(ud.c, 0.f);                           \
            const float dw = accp.c * ap.c * gp - accd.c * ad.c * gd;    \
            wn.c = fminf(fmaxf(w4.c + dw, 0.f), WMAX);                   \
        }
        COMP(x) COMP(y) COMP(z) COMP(w)
#undef COMP

        *reinterpret_cast<float4*>(out_W + widx)    = w4;
        *reinterpret_cast<float4*>(out_Wnew + widx) = wn;
    }
}

// ---------------------------------------------------------------------------
// Trace-filter kernel: xbar_pre_new, u_pot_new, u_dep_new (all tiny).
// ---------------------------------------------------------------------------
__global__ __launch_bounds__(256) void clopath_traces(
    const float* __restrict__ Xd,        // (D,B,N)
    const float* __restrict__ Vpost,     // (B,N)
    const float* __restrict__ xbar_pre,  // (D,B,N)
    const float* __restrict__ u_pot,     // (B,N)
    const float* __restrict__ u_dep,     // (B,N)
    float* __restrict__ out_xbar,        // (D,B,N)
    float* __restrict__ out_upot,        // (B,N)
    float* __restrict__ out_udep)        // (B,N)
{
    const int NXB = DD * BB * NN;  // 262144
    const int NU  = BB * NN;       // 16384
    int i = ((int)blockIdx.x * 256 + (int)threadIdx.x) * 4;
    if (i < NXB) {
        const float4 xb = *reinterpret_cast<const float4*>(xbar_pre + i);
        const float4 xs = *reinterpret_cast<const float4*>(Xd + i);
        float4 r;
        r.x = 0.95f * xb.x + 0.05f * xs.x;
        r.y = 0.95f * xb.y + 0.05f * xs.y;
        r.z = 0.95f * xb.z + 0.05f * xs.z;
        r.w = 0.95f * xb.w + 0.05f * xs.w;
        *reinterpret_cast<float4*>(out_xbar + i) = r;
    } else {
        int j = i - NXB;
        if (j < NU) {
            const float4 u = *reinterpret_cast<const float4*>(u_pot + j);
            const float4 v = *reinterpret_cast<const float4*>(Vpost + j);
            float4 r;
            r.x = 0.9f * u.x + 0.1f * v.x;
            r.y = 0.9f * u.y + 0.1f * v.y;
            r.z = 0.9f * u.z + 0.1f * v.z;
            r.w = 0.9f * u.w + 0.1f * v.w;
            *reinterpret_cast<float4*>(out_upot + j) = r;
        } else {
            j -= NU;
            if (j < NU) {
                const float4 u = *reinterpret_cast<const float4*>(u_dep + j);
                const float4 v = *reinterpret_cast<const float4*>(Vpost + j);
                float4 r;
                r.x = 0.8f * u.x + 0.2f * v.x;
                r.y = 0.8f * u.y + 0.2f * v.y;
                r.z = 0.8f * u.z + 0.2f * v.z;
                r.w = 0.8f * u.w + 0.2f * v.w;
                *reinterpret_cast<float4*>(out_udep + j) = r;
            }
        }
    }
}

extern "C" void kernel_launch(void* const* d_in, const int* in_sizes, int n_in,
                              void* d_out, int out_size, void* d_ws, size_t ws_size,
                              hipStream_t stream) {
    const float* Xd       = (const float*)d_in[0];
    const float* Xpost    = (const float*)d_in[1];
    const float* Vpost    = (const float*)d_in[2];
    const float* xbar_pre = (const float*)d_in[3];
    const float* u_pot    = (const float*)d_in[4];
    const float* u_dep    = (const float*)d_in[5];
    const float* W        = (const float*)d_in[6];
    const float* A_p      = (const float*)d_in[7];
    const float* A_d      = (const float*)d_in[8];
    const float* dmap     = (const float*)d_in[9];

    float* out = (float*)d_out;
    const size_t BNN = (size_t)BB * NN * NN;      // 33554432
    float* out_W    = out;                        // W pre-update copy
    float* out_Wnew = out + BNN;                  // W_new
    float* out_xbar = out + 2 * BNN;              // (D,B,N)
    float* out_upot = out_xbar + (size_t)DD * BB * NN;
    float* out_udep = out_upot + (size_t)BB * NN;

    // Main: N rows, 2 blocks of 256 threads per row (each thread = 4 o's).
    dim3 grid_main(NN * 2);
    clopath_main<<<grid_main, 256, 0, stream>>>(
        Xd, Xpost, xbar_pre, u_pot, u_dep, W, A_p, A_d, dmap,
        out_W, out_Wnew);

    // Traces: (262144 + 16384 + 16384)/4 = 73728 threads -> 288 blocks.
    clopath_traces<<<288, 256, 0, stream>>>(
        Xd, Vpost, xbar_pre, u_pot, u_dep,
        out_xbar, out_upot, out_udep);
}

// Round 2
// 159.487 us; speedup vs baseline: 1.1608x; 1.1608x over previous
//
#include <hip/hip_runtime.h>

#define DD 16
#define BB 8
#define NN 2048
#define WMAX 2.0f

// ---------------------------------------------------------------------------
// Main kernel, d-outer / b-inner:
//   for d: load dmap[d,e,o4] ONCE, accumulate into accp[b]/accd[b] (VGPR
//   arrays) with wave-uniform scalars xbar_pre[d,b,e] / Xd[d,b,e].
// Epilogue per b: dW = accp*A_p*(Xpost*relu(u_pot)) - accd*A_d*relu(u_dep);
//   out_W = W (pre-update copy); out_Wnew = clip(W+dW, 0, WMAX).
// e is wave-uniform (blockIdx only) -> coefficient loads scalarize.
// ---------------------------------------------------------------------------
__global__ __launch_bounds__(256) void clopath_main(
    const float* __restrict__ Xd,        // (D,B,N)
    const float* __restrict__ Xpost,     // (B,N)
    const float* __restrict__ xbar_pre,  // (D,B,N)
    const float* __restrict__ u_pot,     // (B,N)
    const float* __restrict__ u_dep,     // (B,N)
    const float* __restrict__ W,         // (B,N,N)
    const float* __restrict__ A_p,       // (N,N)
    const float* __restrict__ A_d,       // (N,N)
    const float* __restrict__ dmap,      // (D,N,N)
    float* __restrict__ out_W,           // (B,N,N)  pre-update copy
    float* __restrict__ out_Wnew)        // (B,N,N)
{
    // blocks_per_row = (N/4)/256 = 2
    const int e = blockIdx.x >> 1;                                   // uniform
    const int o = ((((int)blockIdx.x & 1) << 8) | (int)threadIdx.x) << 2;
    const size_t eo = (size_t)e * NN + o;

    float4 accp[BB], accd[BB];
#pragma unroll
    for (int b = 0; b < BB; ++b) {
        accp[b] = make_float4(0.f, 0.f, 0.f, 0.f);
        accd[b] = make_float4(0.f, 0.f, 0.f, 0.f);
    }

#pragma unroll
    for (int d = 0; d < DD; ++d) {
        const float4 dmv =
            *reinterpret_cast<const float4*>(dmap + (size_t)d * NN * NN + eo);
#pragma unroll
        for (int b = 0; b < BB; ++b) {
            const float xb = xbar_pre[(d * BB + b) * NN + e];  // wave-uniform
            const float xs = Xd[(d * BB + b) * NN + e];        // wave-uniform
            accp[b].x = fmaf(xb, dmv.x, accp[b].x);
            accp[b].y = fmaf(xb, dmv.y, accp[b].y);
            accp[b].z = fmaf(xb, dmv.z, accp[b].z);
            accp[b].w = fmaf(xb, dmv.w, accp[b].w);
            accd[b].x = fmaf(xs, dmv.x, accd[b].x);
            accd[b].y = fmaf(xs, dmv.y, accd[b].y);
            accd[b].z = fmaf(xs, dmv.z, accd[b].z);
            accd[b].w = fmaf(xs, dmv.w, accd[b].w);
        }
    }

    const float4 ap = *reinterpret_cast<const float4*>(A_p + eo);
    const float4 ad = *reinterpret_cast<const float4*>(A_d + eo);

#pragma unroll
    for (int b = 0; b < BB; ++b) {
        const int bo = b * NN + o;
        const float4 xp = *reinterpret_cast<const float4*>(Xpost + bo);
        const float4 up = *reinterpret_cast<const float4*>(u_pot + bo);
        const float4 ud = *reinterpret_cast<const float4*>(u_dep + bo);

        const size_t widx = (size_t)b * NN * NN + eo;
        const float4 w4 = *reinterpret_cast<const float4*>(W + widx);

        float4 wn;
#define COMP(c)                                                              \
        {                                                                    \
            const float gp = xp.c * fmaxf(up.c, 0.f);                        \
            const float gd = fmaxf(ud.c, 0.f);                               \
            const float dw = accp[b].c * ap.c * gp - accd[b].c * ad.c * gd;  \
            wn.c = fminf(fmaxf(w4.c + dw, 0.f), WMAX);                       \
        }
        COMP(x) COMP(y) COMP(z) COMP(w)
#undef COMP

        *reinterpret_cast<float4*>(out_W + widx)    = w4;
        *reinterpret_cast<float4*>(out_Wnew + widx) = wn;
    }
}

// ---------------------------------------------------------------------------
// Trace-filter kernel: xbar_pre_new, u_pot_new, u_dep_new (all tiny).
// ---------------------------------------------------------------------------
__global__ __launch_bounds__(256) void clopath_traces(
    const float* __restrict__ Xd,        // (D,B,N)
    const float* __restrict__ Vpost,     // (B,N)
    const float* __restrict__ xbar_pre,  // (D,B,N)
    const float* __restrict__ u_pot,     // (B,N)
    const float* __restrict__ u_dep,     // (B,N)
    float* __restrict__ out_xbar,        // (D,B,N)
    float* __restrict__ out_upot,        // (B,N)
    float* __restrict__ out_udep)        // (B,N)
{
    const int NXB = DD * BB * NN;  // 262144
    const int NU  = BB * NN;       // 16384
    int i = ((int)blockIdx.x * 256 + (int)threadIdx.x) * 4;
    if (i < NXB) {
        const float4 xb = *reinterpret_cast<const float4*>(xbar_pre + i);
        const float4 xs = *reinterpret_cast<const float4*>(Xd + i);
        float4 r;
        r.x = 0.95f * xb.x + 0.05f * xs.x;
        r.y = 0.95f * xb.y + 0.05f * xs.y;
        r.z = 0.95f * xb.z + 0.05f * xs.z;
        r.w = 0.95f * xb.w + 0.05f * xs.w;
        *reinterpret_cast<float4*>(out_xbar + i) = r;
    } else {
        int j = i - NXB;
        if (j < NU) {
            const float4 u = *reinterpret_cast<const float4*>(u_pot + j);
            const float4 v = *reinterpret_cast<const float4*>(Vpost + j);
            float4 r;
            r.x = 0.9f * u.x + 0.1f * v.x;
            r.y = 0.9f * u.y + 0.1f * v.y;
            r.z = 0.9f * u.z + 0.1f * v.z;
            r.w = 0.9f * u.w + 0.1f * v.w;
            *reinterpret_cast<float4*>(out_upot + j) = r;
        } else {
            j -= NU;
            if (j < NU) {
                const float4 u = *reinterpret_cast<const float4*>(u_dep + j);
                const float4 v = *reinterpret_cast<const float4*>(Vpost + j);
                float4 r;
                r.x = 0.8f * u.x + 0.2f * v.x;
                r.y = 0.8f * u.y + 0.2f * v.y;
                r.z = 0.8f * u.z + 0.2f * v.z;
                r.w = 0.8f * u.w + 0.2f * v.w;
                *reinterpret_cast<float4*>(out_udep + j) = r;
            }
        }
    }
}

extern "C" void kernel_launch(void* const* d_in, const int* in_sizes, int n_in,
                              void* d_out, int out_size, void* d_ws, size_t ws_size,
                              hipStream_t stream) {
    const float* Xd       = (const float*)d_in[0];
    const float* Xpost    = (const float*)d_in[1];
    const float* Vpost    = (const float*)d_in[2];
    const float* xbar_pre = (const float*)d_in[3];
    const float* u_pot    = (const float*)d_in[4];
    const float* u_dep    = (const float*)d_in[5];
    const float* W        = (const float*)d_in[6];
    const float* A_p      = (const float*)d_in[7];
    const float* A_d      = (const float*)d_in[8];
    const float* dmap     = (const float*)d_in[9];

    float* out = (float*)d_out;
    const size_t BNN = (size_t)BB * NN * NN;      // 33554432
    float* out_W    = out;                        // W pre-update copy
    float* out_Wnew = out + BNN;                  // W_new
    float* out_xbar = out + 2 * BNN;              // (D,B,N)
    float* out_upot = out_xbar + (size_t)DD * BB * NN;
    float* out_udep = out_upot + (size_t)BB * NN;

    // Main: N rows, 2 blocks of 256 threads per row (each thread = 4 o's).
    dim3 grid_main(NN * 2);
    clopath_main<<<grid_main, 256, 0, stream>>>(
        Xd, Xpost, xbar_pre, u_pot, u_dep, W, A_p, A_d, dmap,
        out_W, out_Wnew);

    // Traces: (262144 + 16384 + 16384)/4 = 73728 threads -> 288 blocks.
    clopath_traces<<<288, 256, 0, stream>>>(
        Xd, Vpost, xbar_pre, u_pot, u_dep,
        out_xbar, out_upot, out_udep);
}